// Round 1
// 447.791 us; speedup vs baseline: 1.0386x; 1.0386x over previous
//
#include <hip/hip_runtime.h>
#include <cstdint>
#include <cstddef>

#define NN_TOK 16384
#define ROWS   65536      // B*N
#define CDIM   192
#define HID    384
#define NHEAD  8
#define HD     48
#define QKVO   1152

typedef unsigned short ushort_t;
typedef __bf16 bf16x8 __attribute__((ext_vector_type(8)));
typedef float  f32x4  __attribute__((ext_vector_type(4)));

__device__ __forceinline__ ushort_t f2bf(float f) {
  unsigned int u = __float_as_uint(f);
  u += 0x7fffu + ((u >> 16) & 1u);          // round-to-nearest-even
  return (ushort_t)(u >> 16);
}
__device__ __forceinline__ float bf2f(ushort_t u) {
  return __uint_as_float(((unsigned int)u) << 16);
}

// ---------------- cast x (fp32) -> bf16, vectorized ----------------
__global__ void cast_x(const float* __restrict__ x, ushort_t* __restrict__ xb, int n8) {
  int i = blockIdx.x * blockDim.x + threadIdx.x;
  if (i >= n8) return;
  const float4* src = (const float4*)(x + (size_t)i * 8);
  float4 f0 = src[0], f1 = src[1];
  uint4 pk;
  pk.x = (unsigned)f2bf(f0.x) | ((unsigned)f2bf(f0.y) << 16);
  pk.y = (unsigned)f2bf(f0.z) | ((unsigned)f2bf(f0.w) << 16);
  pk.z = (unsigned)f2bf(f1.x) | ((unsigned)f2bf(f1.y) << 16);
  pk.w = (unsigned)f2bf(f1.z) | ((unsigned)f2bf(f1.w) << 16);
  *(uint4*)(xb + (size_t)i * 8) = pk;
}

// ---------------- K0: combine input projections; Wc in bf16, bc fp32 ----------------
__global__ void combine_w(const float* __restrict__ in_w, const float* __restrict__ in_b,
                          const float* __restrict__ qkv_w, const float* __restrict__ qkv_b,
                          ushort_t* __restrict__ Wcb, float* __restrict__ bc) {
  int o = blockIdx.x;        // 0..1151
  int c = threadIdx.x;       // 0..191
  const float* qw = qkv_w + o * HID;
  float s = 0.f;
  for (int m = 0; m < HID; ++m) s += qw[m] * in_w[m * CDIM + c];
  Wcb[o * CDIM + c] = f2bf(s);
  if (c == 0) {
    float sb = qkv_b[o];
    for (int m = 0; m < HID; ++m) sb += qw[m] * in_b[m];
    bc[o] = sb;
  }
}

// cast out_w (192x384 fp32) -> bf16
__global__ void cast_ow(const float* __restrict__ w, ushort_t* __restrict__ wb, int n) {
  int i = blockIdx.x * blockDim.x + threadIdx.x;
  if (i < n) wb[i] = f2bf(w[i]);
}

// ---------------- packed rope table: tab4[n][dp] = (cos1,sin1,cos2,sin2), dp<24 ----------------
__global__ void build_tab(float4* __restrict__ tab4) {
  int i = blockIdx.x * blockDim.x + threadIdx.x;
  if (i >= NN_TOK * 24) return;
  int n = i / 24, dp = i - n * 24;
  int j = dp % 12;
  const float c0 = 1.1073093649624542f;   // log2(10000)/12
  float freq = exp2f(-(float)j * c0);
  float fy = (float)(n >> 7), fx = (float)(n & 127);
  float s1, c1, s2, c2;
  sincosf(fy * freq, &s1, &c1);
  sincosf(fx * freq, &s2, &c2);
  tab4[i] = make_float4(c1, s1, c2, s2);
}

// ---------------- MFMA bf16 GEMM: C[n,o] = sum_k A[n,k]*W[o,k] + bias[o] ----------------
// A bf16 with row stride lda; W (O,K) bf16 dense; C stride O (fp32 or bf16).
template<int BM, int BN, int WM, int WN, bool OUTBF16>
__global__ __launch_bounds__(256) void gemm_mfma(const ushort_t* __restrict__ A, int lda,
                                                 const ushort_t* __restrict__ Wb,
                                                 const float* __restrict__ bias,
                                                 void* __restrict__ Cptr,
                                                 int K, int O) {
  constexpr int TM = BM / WM / 16;
  constexpr int TN = BN / WN / 16;
  __shared__ __align__(16) ushort_t As[BM][40];
  __shared__ __align__(16) ushort_t Bs[BN][40];
  const int t    = threadIdx.x;
  const int lane = t & 63;
  const int wave = t >> 6;
  const int quad = lane >> 4;
  const int l15  = lane & 15;
  const int wm   = wave / WN, wn = wave % WN;
  const int m_base = wm * (BM / WM);
  const int n_base = wn * (BN / WN);
  const int n0 = blockIdx.y * BM;
  const int o0 = blockIdx.x * BN;
  f32x4 acc[TM][TN] = {};

  for (int kt = 0; kt < K; kt += 32) {
    for (int c = t; c < BM * 4; c += 256) {
      int row = c >> 2, col8 = (c & 3) * 8;
      *(uint4*)&As[row][col8] = *(const uint4*)(A + (size_t)(n0 + row) * lda + kt + col8);
    }
    for (int c = t; c < BN * 4; c += 256) {
      int row = c >> 2, col8 = (c & 3) * 8;
      *(uint4*)&Bs[row][col8] = *(const uint4*)(Wb + (size_t)(o0 + row) * K + kt + col8);
    }
    __syncthreads();
    bf16x8 af[TM], bfr[TN];
#pragma unroll
    for (int mi = 0; mi < TM; ++mi)
      af[mi] = *(const bf16x8*)&As[m_base + mi * 16 + l15][quad * 8];
#pragma unroll
    for (int ni = 0; ni < TN; ++ni)
      bfr[ni] = *(const bf16x8*)&Bs[n_base + ni * 16 + l15][quad * 8];
#pragma unroll
    for (int mi = 0; mi < TM; ++mi)
#pragma unroll
      for (int ni = 0; ni < TN; ++ni)
        acc[mi][ni] = __builtin_amdgcn_mfma_f32_16x16x32_bf16(af[mi], bfr[ni], acc[mi][ni], 0, 0, 0);
    __syncthreads();
  }
#pragma unroll
  for (int mi = 0; mi < TM; ++mi) {
#pragma unroll
    for (int ni = 0; ni < TN; ++ni) {
      int col = o0 + n_base + ni * 16 + l15;
      float bv = bias[col];
      int rbase = n0 + m_base + mi * 16 + quad * 4;
#pragma unroll
      for (int r = 0; r < 4; ++r) {
        float val = acc[mi][ni][r] + bv;
        if (OUTBF16) ((ushort_t*)Cptr)[(size_t)(rbase + r) * O + col] = f2bf(val);
        else         ((float*)Cptr)[(size_t)(rbase + r) * O + col] = val;
      }
    }
  }
}

// ---------------- kv partials via MFMA: fused RoPE+elu(k) and lepe conv(v) staged as
// bf16 fragments; KV[48][48] = sum_n k[n][d]*v[n][e] on the matrix pipe. ----------------
// LDS fragment layout [dg][nblk][16 d][8 n]: lane's A/B fragment (8 contiguous n for
// fixed d/e) is one aligned ds_read_b128. C-layout: col=lane&15, row=(lane>>4)*4+reg.
// grid 2048 = bh(32)*chunk(64), 256 rows/chunk, 2 iters x 128 staged rows.
__global__ __launch_bounds__(256) void kv_partial_k(const ushort_t* __restrict__ kq,
                                                    const ushort_t* __restrict__ vq,
                                                    const float4* __restrict__ tab4,
                                                    const float* __restrict__ lw,
                                                    const float* __restrict__ lb,
                                                    float* __restrict__ part) {
  const int bid   = blockIdx.x;
  const int chunk = bid & 63;
  const int bh    = bid >> 6;         // 0..31
  const int b     = bh >> 3;
  const int h     = bh & 7;
  const int t     = threadIdx.x;
  const int lane  = t & 63;
  const int wave  = t >> 6;
  __shared__ __align__(16) ushort_t ksF[3][16][16][8];   // 12 KB bf16 fragments of k^T
  __shared__ __align__(16) ushort_t vsF[3][16][16][8];   // 12 KB bf16 fragments of v
  __shared__ float wlds[9][48];
  __shared__ float blds[48];
  float* red   = (float*)&ksF[0][0][0][0];   // 2304 floats, aliased after main loop
  float* ksred = (float*)&vsF[0][0][0][0];   // 4*48 floats, aliased after main loop
  for (int c = t; c < 432; c += 256) {
    int ch = c / 9, tap = c - ch * 9;
    wlds[tap][ch] = lw[(h * HD + ch) * 9 + tap];
  }
  if (t < 48) blds[t] = lb[h * HD + t];
  __syncthreads();

  const int g  = lane >> 4;          // 0..3 (fragment k-group)
  const int d0 = lane & 15;          // fragment row/col within 16
  f32x4 acc[3][3] = {};              // 9 MFMA tiles = full 48x48 per-wave partial
  float ksacc = 0.f;
  const int n0 = b * NN_TOK + chunk * 256;

  for (int it = 0; it < 2; ++it) {
    const int nbase = it * 128;
    // ---- k staging: rope+elu -> bf16 fragment layout; 128 rows x 3 segs of 8 pairs ----
    for (int c = t; c < 384; c += 256) {
      int rr = c / 3, s8 = (c - (c / 3) * 3) * 8;
      int n  = n0 + nbase + rr;
      int nn = n & (NN_TOK - 1);
      const ushort_t* kr = kq + (size_t)n * QKVO + h * HD;
      uint4 ka = *(const uint4*)(kr + s8);
      uint4 kb = *(const uint4*)(kr + s8 + 24);
      ushort_t ua[8], ub[8];
      *(uint4*)ua = ka; *(uint4*)ub = kb;
      const float4* t4 = tab4 + nn * 24 + s8;
      const int nb = rr >> 3, nm = rr & 7;
#pragma unroll
      for (int jj = 0; jj < 8; ++jj) {
        float4 cs = t4[jj];
        float in1 = bf2f(ua[jj]), in2 = bf2f(ub[jj]);
        float o1 = in1 * cs.x - in2 * cs.y;
        float o2 = in2 * cs.z + in1 * cs.w;
        o1 = (o1 > 0.f) ? o1 + 1.f : expf(o1);
        o2 = (o2 > 0.f) ? o2 + 1.f : expf(o2);
        const int d1 = s8 + jj, d2 = s8 + 24 + jj;
        ksF[d1 >> 4][nb][d1 & 15][nm] = f2bf(o1);
        ksF[d2 >> 4][nb][d2 & 15][nm] = f2bf(o2);
      }
    }
    // ---- v staging with fused lepe conv: 128 pixels (full image row) x 6 ch-groups ----
    {
      const int nst = chunk * 256 + nbase;   // 128-aligned -> fixed y
      const int y   = nst >> 7;
      for (int c = t; c < 768; c += 256) {
        int rr = c / 6, gg = c - (c / 6) * 6;
        int x = rr;
        float a8[8], ctr[8];
#pragma unroll
        for (int ci = 0; ci < 8; ++ci) a8[ci] = blds[gg * 8 + ci];
#pragma unroll
        for (int dy = -1; dy <= 1; ++dy) {
#pragma unroll
          for (int dx = -1; dx <= 1; ++dx) {
            int yy = y + dy, xx = x + dx;
            float m = ((unsigned)yy < 128u && (unsigned)xx < 128u) ? 1.f : 0.f;
            int yc = min(max(yy, 0), 127), xc = min(max(xx, 0), 127);
            const ushort_t* src = vq + ((size_t)(b * NN_TOK + (yc << 7) + xc)) * QKVO + h * HD + gg * 8;
            uint4 pk = *(const uint4*)src;
            ushort_t uu[8];
            *(uint4*)uu = pk;
            const int tap = (dy + 1) * 3 + (dx + 1);
#pragma unroll
            for (int ci = 0; ci < 8; ++ci) {
              float val = bf2f(uu[ci]);
              if (dy == 0 && dx == 0) ctr[ci] = val;
              a8[ci] += (wlds[tap][gg * 8 + ci] * m) * val;
            }
          }
        }
        const int nb = rr >> 3, nm = rr & 7;
#pragma unroll
        for (int ci = 0; ci < 8; ++ci) {
          const int e = gg * 8 + ci;
          vsF[e >> 4][nb][e & 15][nm] = f2bf(ctr[ci] + a8[ci]);
        }
      }
    }
    __syncthreads();
    // ---- MFMA: each wave reduces its 32 rows (K=32) into 9 accumulator tiles ----
    {
      const int w4 = wave * 4 + g;     // nblk for this lane's fragment
      bf16x8 af[3], bfr[3];
#pragma unroll
      for (int dg = 0; dg < 3; ++dg) af[dg]  = *(const bf16x8*)&ksF[dg][w4][d0][0];
#pragma unroll
      for (int eg = 0; eg < 3; ++eg) bfr[eg] = *(const bf16x8*)&vsF[eg][w4][d0][0];
#pragma unroll
      for (int dg = 0; dg < 3; ++dg)
#pragma unroll
        for (int eg = 0; eg < 3; ++eg)
          acc[dg][eg] = __builtin_amdgcn_mfma_f32_16x16x32_bf16(af[dg], bfr[eg], acc[dg][eg], 0, 0, 0);
    }
    // ---- ksum: lane<48 sums k over this wave's 32 rows (bf16 scalar reads) ----
    if (lane < 48) {
      const int dg = lane >> 4, dd = lane & 15;
#pragma unroll 8
      for (int rr = 0; rr < 32; ++rr) {
        int nl = wave * 32 + rr;
        ksacc += bf2f(ksF[dg][nl >> 3][dd][nl & 7]);
      }
    }
    __syncthreads();
  }
  // cross-wave reduce (red/ksred alias ksF/vsF; all MFMA reads complete)
  if (wave == 0) {
#pragma unroll
    for (int dg = 0; dg < 3; ++dg)
#pragma unroll
      for (int eg = 0; eg < 3; ++eg)
#pragma unroll
        for (int r = 0; r < 4; ++r)
          red[(dg * 16 + g * 4 + r) * 48 + eg * 16 + d0] = acc[dg][eg][r];
  }
  if (lane < 48) ksred[wave * 48 + lane] = ksacc;
  __syncthreads();
  for (int w = 1; w < 4; ++w) {
    if (wave == w) {
#pragma unroll
      for (int dg = 0; dg < 3; ++dg)
#pragma unroll
        for (int eg = 0; eg < 3; ++eg)
#pragma unroll
          for (int r = 0; r < 4; ++r)
            red[(dg * 16 + g * 4 + r) * 48 + eg * 16 + d0] += acc[dg][eg][r];
    }
    __syncthreads();
  }
  float* p = part + (size_t)bid * 2352;
  for (int c = t; c < 2304; c += 256) p[c] = red[c];
  if (t < 48) p[2304 + t] = ksred[t] + ksred[48 + t] + ksred[96 + t] + ksred[144 + t];
}

// phase 2: sum 64 chunk-partials per bh -> kv (32x2304) and ksum (32x48)
__global__ void kv_phase2(const float* __restrict__ part, float* __restrict__ kvb,
                          float* __restrict__ ksum) {
  int bh  = blockIdx.x >> 3;
  int seg = blockIdx.x & 7;
  int t   = threadIdx.x;
  int cend = (seg + 1) * 294;
  for (int c = seg * 294 + t; c < cend; c += 256) {
    const float* p = part + (size_t)(bh * 64) * 2352 + c;
    float s = 0.f;
    for (int ch = 0; ch < 64; ++ch) s += p[(size_t)ch * 2352];
    if (c < 2304) kvb[bh * 2304 + c] = s;
    else          ksum[bh * 48 + (c - 2304)] = s;
  }
}

// ---------------- fused: rope+elu(q) -> q@kv/denom -> LayerNorm -> oln (bf16, strided) ----------------
// q bf16 slice of qkvb (stride 1152); oln written into k slice (stride 1152).
__global__ __launch_bounds__(256) void attn_ln_fused(const ushort_t* __restrict__ q,
                                                     const float4* __restrict__ tab4,
                                                     const float* __restrict__ kvg,
                                                     const float* __restrict__ ksum,
                                                     const float* __restrict__ ln_g,
                                                     const float* __restrict__ ln_b,
                                                     ushort_t* __restrict__ oln) {
  __shared__ __align__(16) float qs[32][8][52];
  __shared__ float denomS[32][8];
  const int t    = threadIdx.x;
  const int row0 = blockIdx.x * 32;
  const int b    = row0 >> 14;
  // ---- Phase A: stage q (bf16 -> fp32 LDS) ----
  for (int c = t; c < 1536; c += 256) {
    int r = c / 48, g = c - (c / 48) * 48;
    int h = g / 6, d = (g - h * 6) * 8;
    uint4 pk = *(const uint4*)(q + (size_t)(row0 + r) * QKVO + g * 8);
    ushort_t uu[8];
    *(uint4*)uu = pk;
    *(float4*)&qs[r][h][d]     = make_float4(bf2f(uu[0]), bf2f(uu[1]), bf2f(uu[2]), bf2f(uu[3]));
    *(float4*)&qs[r][h][d + 4] = make_float4(bf2f(uu[4]), bf2f(uu[5]), bf2f(uu[6]), bf2f(uu[7]));
  }
  __syncthreads();
  // ---- Phase B: rope+elu in LDS + denom ----
  {
    int r = t >> 3, h = t & 7;
    int n = (row0 + r) & (NN_TOK - 1);
    const float4* t4 = tab4 + n * 24;
    const float* ksh = ksum + (b * 8 + h) * 48;
    float dn = 0.f;
#pragma unroll 4
    for (int dp = 0; dp < 24; ++dp) {
      float4 cs = t4[dp];
      float in1 = qs[r][h][dp], in2 = qs[r][h][dp + 24];
      float o1 = in1 * cs.x - in2 * cs.y;
      float o2 = in2 * cs.z + in1 * cs.w;
      o1 = (o1 > 0.f) ? o1 + 1.f : expf(o1);
      o2 = (o2 > 0.f) ? o2 + 1.f : expf(o2);
      qs[r][h][dp]      = o1;
      qs[r][h][dp + 24] = o2;
      dn += o1 * ksh[dp] + o2 * ksh[dp + 24];
    }
    denomS[r][h] = fmaxf(dn, 1e-6f);
  }
  __syncthreads();
  // ---- Phase C: q@kv, 8x6 register tile per lane ----
  const int lane = t & 63, rg = t >> 6;
  const int hh = lane >> 3;
  const int e0 = (lane & 7) * 6;
  const float* kvh = kvg + (size_t)(b * 8 + hh) * 48 * 48;
  float acc[8][6] = {};
#pragma unroll 2
  for (int d = 0; d < 48; ++d) {
    float kvv[6];
    *(float2*)&kvv[0] = *(const float2*)(kvh + d * 48 + e0);
    *(float2*)&kvv[2] = *(const float2*)(kvh + d * 48 + e0 + 2);
    *(float2*)&kvv[4] = *(const float2*)(kvh + d * 48 + e0 + 4);
#pragma unroll
    for (int i = 0; i < 8; ++i) {
      float qv = qs[rg * 8 + i][hh][d];
#pragma unroll
      for (int j = 0; j < 6; ++j) acc[i][j] += qv * kvv[j];
    }
  }
  // ---- Phase D: divide, LN (wave shuffle), store bf16 strided ----
  float gg[6], bb[6];
#pragma unroll
  for (int j = 0; j < 6; ++j) {
    gg[j] = ln_g[lane * 6 + j];
    bb[j] = ln_b[lane * 6 + j];
  }
#pragma unroll
  for (int i = 0; i < 8; ++i) {
    int r = rg * 8 + i;
    float dnm = denomS[r][hh];
    float o[6];
    float s = 0.f, sq = 0.f;
#pragma unroll
    for (int j = 0; j < 6; ++j) {
      o[j] = acc[i][j] / dnm;
      s += o[j]; sq += o[j] * o[j];
    }
#pragma unroll
    for (int m = 1; m < 64; m <<= 1) {
      s  += __shfl_xor(s, m, 64);
      sq += __shfl_xor(sq, m, 64);
    }
    float mu   = s * (1.f / 384.f);
    float var  = sq * (1.f / 384.f) - mu * mu;
    float rstd = rsqrtf(var + 1e-5f);
    unsigned pk0 = (unsigned)f2bf((o[0] - mu) * rstd * gg[0] + bb[0]) |
                   ((unsigned)f2bf((o[1] - mu) * rstd * gg[1] + bb[1]) << 16);
    unsigned pk1 = (unsigned)f2bf((o[2] - mu) * rstd * gg[2] + bb[2]) |
                   ((unsigned)f2bf((o[3] - mu) * rstd * gg[3] + bb[3]) << 16);
    unsigned pk2 = (unsigned)f2bf((o[4] - mu) * rstd * gg[4] + bb[4]) |
                   ((unsigned)f2bf((o[5] - mu) * rstd * gg[5] + bb[5]) << 16);
    unsigned* dst = (unsigned*)(oln + (size_t)(row0 + r) * QKVO + lane * 6);
    dst[0] = pk0; dst[1] = pk1; dst[2] = pk2;
  }
}

extern "C" void kernel_launch(void* const* d_in, const int* in_sizes, int n_in,
                              void* d_out, int out_size, void* d_ws, size_t ws_size,
                              hipStream_t stream) {
  const float* x      = (const float*)d_in[0];
  const float* in_w   = (const float*)d_in[1];
  const float* in_b   = (const float*)d_in[2];
  const float* qkv_w  = (const float*)d_in[3];
  const float* qkv_b  = (const float*)d_in[4];
  const float* lepe_w = (const float*)d_in[5];
  const float* lepe_b = (const float*)d_in[6];
  const float* ln_g   = (const float*)d_in[7];
  const float* ln_b   = (const float*)d_in[8];
  const float* out_w  = (const float*)d_in[9];
  const float* out_b  = (const float*)d_in[10];
  float* out = (float*)d_out;

  // workspace (float units) ~183 MB total
  float*    ws     = (float*)d_ws;
  float*    qkvbF  = ws;                                     // ROWS*1152/2 = 37748736
  float*    xbF    = qkvbF + (size_t)ROWS * QKVO / 2;        // ROWS*192/2  = 6291456 (aliased by part)
  float*    WcbF   = xbF   + (size_t)ROWS * CDIM / 2;        // 110592
  float*    bc     = WcbF  + (size_t)QKVO * CDIM / 2;        // 1152
  float*    owbF   = bc    + QKVO;                           // 36864
  float*    kvb    = owbF  + (size_t)CDIM * HID / 2;         // 73728
  float*    ksum   = kvb   + 32 * HD * HD;                   // 1536
  float*    tab4F  = ksum  + 32 * HD;                        // 16384*24*4 = 1572864
  ushort_t* qkvb   = (ushort_t*)qkvbF;
  ushort_t* xb     = (ushort_t*)xbF;
  float*    part   = xbF;                                    // alias: xb dead after QKV GEMM (4816896 < 6291456)
  ushort_t* Wcb    = (ushort_t*)WcbF;
  ushort_t* owb    = (ushort_t*)owbF;
  float4*   tab4   = (float4*)tab4F;

  // prep
  cast_x<<<(ROWS * CDIM / 8 + 255) / 256, 256, 0, stream>>>(x, xb, ROWS * CDIM / 8);
  combine_w<<<QKVO, CDIM, 0, stream>>>(in_w, in_b, qkv_w, qkv_b, Wcb, bc);
  cast_ow<<<(CDIM * HID + 255) / 256, 256, 0, stream>>>(out_w, owb, CDIM * HID);
  build_tab<<<(NN_TOK * 24 + 255) / 256, 256, 0, stream>>>(tab4);

  // fused QKV projection: qkvb = xb @ Wcb^T + bc (bf16 out)
  dim3 gqkv(QKVO / 128, ROWS / 128);       // (9, 512)
  gemm_mfma<128, 128, 2, 2, true><<<gqkv, 256, 0, stream>>>(xb, CDIM, Wcb, bc, qkvb, CDIM, QKVO);

  // kv reduction with fused rope(k) + lepe conv(v), MFMA outer product
  kv_partial_k<<<2048, 256, 0, stream>>>(qkvb + HID, qkvb + 2 * HID, tab4, lepe_w, lepe_b, part);
  kv_phase2<<<256, 256, 0, stream>>>(part, kvb, ksum);

  // fused rope(q) + attention + LN -> oln written into k slice of qkvb
  attn_ln_fused<<<ROWS / 32, 256, 0, stream>>>(qkvb, tab4, kvb, ksum, ln_g, ln_b, qkvb + HID);

  // final projection: oln (bf16, stride 1152) @ out_w^T -> out (fp32)
  dim3 g6(CDIM / 64, ROWS / 128);          // (3, 512)
  gemm_mfma<128, 64, 4, 1, false><<<g6, 256, 0, stream>>>(qkvb + HID, QKVO, owb, out_b, out, HID, CDIM);
}